// Round 5
// baseline (767.696 us; speedup 1.0000x reference)
//
#include <hip/hip_runtime.h>
#include <hip/hip_bf16.h>

#define TT 2048
#define BB 512
#define HH 32
#define NPAIR (TT * BB)
#define PSTRIDE (BB * HH)   // floats per t-slice of P = 16384

// tanh(u) = 1 - 2/(1+e^{2u}); exact at both saturations.
__device__ __forceinline__ float fast_tanh(float u) {
    float e = exp2f(u * 2.88539008177792681f);          // e^{2u} via v_exp_f32
    return 1.0f - 2.0f * __builtin_amdgcn_rcpf(e + 1.0f);
}

// ---------------- Pass 1: P[t][row][j] = b[j] + emb[x[t,row]] @ Wx[:,j] ----------------
// Each 32-lane group handles 16 consecutive pairs. The emb row is fetched with ONE
// coalesced dword load per pair (lane jj reads emb[idx*32+jj]) -- 16 rows in flight
// (2 KB MLP per group). Rows staged via LDS (write bank=lane: conflict-free; readback
// broadcast: free), then the 32-FMA matvec per pair as before.
__global__ __launch_bounds__(256) void precompute_v5(
        const int* __restrict__ x, const float* __restrict__ emb,
        const float* __restrict__ W_rnn, const float* __restrict__ b_rnn,
        float* __restrict__ P) {
    const int tid = threadIdx.x;
    const int jj  = tid & 31;
    const int l   = tid & 63;           // lane in wave
    const int grp = tid >> 5;           // group in block (0..7)
    const int g   = (blockIdx.x * 256 + tid) >> 5;   // global group
    const int pair0 = g * 16;

    __shared__ float stage[8][16][HH];  // 16 KB per block

    float wx[32];
#pragma unroll
    for (int k = 0; k < 32; ++k) wx[k] = W_rnn[k * HH + jj];
    const float bj = b_rnn[jj];

    // One coalesced load gives the group its 16 indices (lanes 16-31 duplicate).
    const int idxv  = x[pair0 + (jj & 15)];
    const int bbase = (l & 32) * 4;     // bpermute byte base for this wave-half

    // Gather all 16 rows: bpermute the per-pair index to all lanes of the half,
    // then one coalesced dword load per pair.  All 16 loads go out together.
    float ev[16];
#pragma unroll
    for (int i = 0; i < 16; ++i) {
        int pi = __builtin_amdgcn_ds_bpermute(bbase + 4 * i, idxv);
        ev[i] = emb[(size_t)pi * HH + jj];
    }
#pragma unroll
    for (int i = 0; i < 16; ++i)
        stage[grp][i][jj] = ev[i];      // bank = jj: conflict-free (2-way across halves)

    // Matvec per pair: broadcast readback (same addr within group) + 32 FMA.
#pragma unroll 4
    for (int i = 0; i < 16; ++i) {
        const float4* sp = (const float4*)&stage[grp][i][0];
        float u0 = bj, u1 = 0.f, u2 = 0.f, u3 = 0.f;
#pragma unroll
        for (int q = 0; q < 8; ++q) {
            float4 e = sp[q];
            u0 = fmaf(e.x, wx[4*q+0], u0);
            u1 = fmaf(e.y, wx[4*q+1], u1);
            u2 = fmaf(e.z, wx[4*q+2], u2);
            u3 = fmaf(e.w, wx[4*q+3], u3);
        }
        P[(size_t)(pair0 + i) * HH + jj] = (u0 + u1) + (u2 + u3);
    }
}

// ---------------- Pass 2: sequential scan, 2 DISTINCT rows per wave --------------------
// Lanes 0-31 = row 2*blk, lanes 32-63 = row 2*blk+1.  h-broadcast via ds_bpermute
// (lane l reads h[(l&32)+k] -- one inst serves both halves; DS pipe overlaps VALU).
// P lives in REGISTERS: 16-deep double-buffered strided dword loads (coalesced 256 B
// per wave-inst, issued 16 steps = ~2k cyc ahead of use). Zero per-step memory ops.
__global__ __launch_bounds__(64) void rnn_seq_v5(
        const float* __restrict__ P, const float* __restrict__ W_rnn,
        const float* __restrict__ W_cls, const float* __restrict__ b_cls,
        float* __restrict__ out) {
    const int l   = threadIdx.x;
    const int jj  = l & 31;
    const int row = blockIdx.x * 2 + (l >> 5);

    float wh[32];
#pragma unroll
    for (int k = 0; k < 32; ++k) wh[k] = W_rnn[(HH + k) * HH + jj];

    const int bbase = (l & 32) * 4;                       // bpermute half base
    const float* gptr = P + (size_t)blockIdx.x * 64 + l;  // = row*HH + jj

    float pA[16], pB[16];
#pragma unroll
    for (int i = 0; i < 16; ++i) pA[i] = gptr[(size_t)i * PSTRIDE];

    float h = 0.0f;

#pragma unroll 1
    for (int e2 = 0; e2 < TT / 32; ++e2) {
        const int tB = e2 * 32 + 16;
#pragma unroll
        for (int i = 0; i < 16; ++i) pB[i] = gptr[(size_t)(tB + i) * PSTRIDE];

#pragma unroll
        for (int s = 0; s < 16; ++s) {
            const int hb = __float_as_int(h);
            float u0 = pA[s], u1 = 0.f, u2 = 0.f, u3 = 0.f;
            float u4 = 0.f, u5 = 0.f, u6 = 0.f, u7 = 0.f;
#pragma unroll
            for (int k = 0; k < 32; k += 8) {
                u0 = fmaf(__int_as_float(__builtin_amdgcn_ds_bpermute(bbase + 4*(k+0), hb)), wh[k+0], u0);
                u1 = fmaf(__int_as_float(__builtin_amdgcn_ds_bpermute(bbase + 4*(k+1), hb)), wh[k+1], u1);
                u2 = fmaf(__int_as_float(__builtin_amdgcn_ds_bpermute(bbase + 4*(k+2), hb)), wh[k+2], u2);
                u3 = fmaf(__int_as_float(__builtin_amdgcn_ds_bpermute(bbase + 4*(k+3), hb)), wh[k+3], u3);
                u4 = fmaf(__int_as_float(__builtin_amdgcn_ds_bpermute(bbase + 4*(k+4), hb)), wh[k+4], u4);
                u5 = fmaf(__int_as_float(__builtin_amdgcn_ds_bpermute(bbase + 4*(k+5), hb)), wh[k+5], u5);
                u6 = fmaf(__int_as_float(__builtin_amdgcn_ds_bpermute(bbase + 4*(k+6), hb)), wh[k+6], u6);
                u7 = fmaf(__int_as_float(__builtin_amdgcn_ds_bpermute(bbase + 4*(k+7), hb)), wh[k+7], u7);
            }
            h = fast_tanh(((u0 + u1) + (u2 + u3)) + ((u4 + u5) + (u6 + u7)));
        }

        int tA = e2 * 32 + 32;
        if (tA > TT - 16) tA = TT - 16;   // last reload redundant but in-bounds
#pragma unroll
        for (int i = 0; i < 16; ++i) pA[i] = gptr[(size_t)(tA + i) * PSTRIDE];

#pragma unroll
        for (int s = 0; s < 16; ++s) {
            const int hb = __float_as_int(h);
            float u0 = pB[s], u1 = 0.f, u2 = 0.f, u3 = 0.f;
            float u4 = 0.f, u5 = 0.f, u6 = 0.f, u7 = 0.f;
#pragma unroll
            for (int k = 0; k < 32; k += 8) {
                u0 = fmaf(__int_as_float(__builtin_amdgcn_ds_bpermute(bbase + 4*(k+0), hb)), wh[k+0], u0);
                u1 = fmaf(__int_as_float(__builtin_amdgcn_ds_bpermute(bbase + 4*(k+1), hb)), wh[k+1], u1);
                u2 = fmaf(__int_as_float(__builtin_amdgcn_ds_bpermute(bbase + 4*(k+2), hb)), wh[k+2], u2);
                u3 = fmaf(__int_as_float(__builtin_amdgcn_ds_bpermute(bbase + 4*(k+3), hb)), wh[k+3], u3);
                u4 = fmaf(__int_as_float(__builtin_amdgcn_ds_bpermute(bbase + 4*(k+4), hb)), wh[k+4], u4);
                u5 = fmaf(__int_as_float(__builtin_amdgcn_ds_bpermute(bbase + 4*(k+5), hb)), wh[k+5], u5);
                u6 = fmaf(__int_as_float(__builtin_amdgcn_ds_bpermute(bbase + 4*(k+6), hb)), wh[k+6], u6);
                u7 = fmaf(__int_as_float(__builtin_amdgcn_ds_bpermute(bbase + 4*(k+7), hb)), wh[k+7], u7);
            }
            h = fast_tanh(((u0 + u1) + (u2 + u3)) + ((u4 + u5) + (u6 + u7)));
        }
    }

    // Epilogue: y = h @ W_cls + b_cls (N_CLASS=5); all lanes run the bpermutes
    // (cross-lane ops need full participation), lanes jj<5 of each half store.
    {
        const int c = (jj < 5) ? jj : 4;
        const int hb = __float_as_int(h);
        float acc = b_cls[c];
#pragma unroll
        for (int k = 0; k < 32; ++k) {
            float hk = __int_as_float(__builtin_amdgcn_ds_bpermute(bbase + 4*k, hb));
            acc = fmaf(hk, W_cls[k * 5 + c], acc);
        }
        if (jj < 5) out[row * 5 + jj] = acc;
    }
}

// ---------------- Fallback (fused) for tiny workspace ----------------------------------
__device__ __forceinline__ float rnn_step_fb(const float4 xt[8], const float wx[32],
                                             const float wh[32], float bj,
                                             float* hrow, int lane) {
    float u0 = 0.f, u1 = 0.f, u2 = 0.f, u3 = 0.f;
#pragma unroll
    for (int q = 0; q < 8; ++q) {
        u0 = fmaf(xt[q].x, wx[4*q+0], u0);
        u1 = fmaf(xt[q].y, wx[4*q+1], u1);
        u2 = fmaf(xt[q].z, wx[4*q+2], u2);
        u3 = fmaf(xt[q].w, wx[4*q+3], u3);
    }
    const float4* hp = (const float4*)hrow;
#pragma unroll
    for (int q = 0; q < 8; ++q) {
        float4 hv = hp[q];
        u0 = fmaf(hv.x, wh[4*q+0], u0);
        u1 = fmaf(hv.y, wh[4*q+1], u1);
        u2 = fmaf(hv.z, wh[4*q+2], u2);
        u3 = fmaf(hv.w, wh[4*q+3], u3);
    }
    float hn = fast_tanh(bj + ((u0 + u1) + (u2 + u3)));
    hrow[lane] = hn;
    return hn;
}

__global__ __launch_bounds__(64) void rnn_seq_kernel(
        const int* __restrict__ x, const float* __restrict__ emb,
        const float* __restrict__ W_rnn, const float* __restrict__ b_rnn,
        const float* __restrict__ W_cls, const float* __restrict__ b_cls,
        float* __restrict__ out) {
    const int lane = threadIdx.x & 31;
    const int grp  = threadIdx.x >> 5;
    const int row  = blockIdx.x * 2 + grp;
    __shared__ float hbuf[2][HH];
    float wx[32], wh[32];
#pragma unroll
    for (int k = 0; k < 32; ++k) {
        wx[k] = W_rnn[k * HH + lane];
        wh[k] = W_rnn[(HH + k) * HH + lane];
    }
    const float bj = b_rnn[lane];
    hbuf[grp][lane] = 0.0f;
    float* hrow = &hbuf[grp][0];
    int i1 = x[1 * BB + row];
    float4 xcur[8], xnxt[8];
    {
        int i0 = x[0 * BB + row];
        const float4* ep = (const float4*)(emb + (size_t)i0 * HH);
#pragma unroll
        for (int q = 0; q < 8; ++q) xcur[q] = ep[q];
    }
    for (int t = 0; t < TT; t += 2) {
        int i2 = x[min(t + 2, TT - 1) * BB + row];
        {
            const float4* ep = (const float4*)(emb + (size_t)i1 * HH);
#pragma unroll
            for (int q = 0; q < 8; ++q) xnxt[q] = ep[q];
        }
        rnn_step_fb(xcur, wx, wh, bj, hrow, lane);
        i1 = x[min(t + 3, TT - 1) * BB + row];
        {
            const float4* ep = (const float4*)(emb + (size_t)i2 * HH);
#pragma unroll
            for (int q = 0; q < 8; ++q) xcur[q] = ep[q];
        }
        rnn_step_fb(xnxt, wx, wh, bj, hrow, lane);
    }
    if (lane < 5) {
        float acc = b_cls[lane];
#pragma unroll
        for (int k = 0; k < 32; ++k)
            acc = fmaf(hrow[k], W_cls[k * 5 + lane], acc);
        out[row * 5 + lane] = acc;
    }
}

extern "C" void kernel_launch(void* const* d_in, const int* in_sizes, int n_in,
                              void* d_out, int out_size, void* d_ws, size_t ws_size,
                              hipStream_t stream) {
    const int*   x     = (const int*)d_in[0];
    const float* emb   = (const float*)d_in[1];
    const float* W_rnn = (const float*)d_in[2];
    const float* b_rnn = (const float*)d_in[3];
    const float* W_cls = (const float*)d_in[4];
    const float* b_cls = (const float*)d_in[5];
    float* out = (float*)d_out;

    const size_t need32 = (size_t)NPAIR * HH * 4;   // 128 MiB
    if (ws_size >= need32) {
        float* P = (float*)d_ws;
        const int pre_blocks = NPAIR / (16 * 8);    // 8192 blocks x 256 thr
        precompute_v5<<<pre_blocks, 256, 0, stream>>>(x, emb, W_rnn, b_rnn, P);
        rnn_seq_v5<<<BB / 2, 64, 0, stream>>>(P, W_rnn, W_cls, b_cls, out);
    } else {
        rnn_seq_kernel<<<BB / 2, 64, 0, stream>>>(x, emb, W_rnn, b_rnn, W_cls, b_cls, out);
    }
}

// Round 6
// 540.770 us; speedup vs baseline: 1.4196x; 1.4196x over previous
//
#include <hip/hip_runtime.h>
#include <hip/hip_bf16.h>

#define TT 2048
#define BB 512
#define HH 32
#define NPAIR (TT * BB)
#define PSTRIDE (BB * HH)   // floats per t-slice of P = 16384

// tanh(u) = 1 - 2/(1+e^{2u}); exact at both saturations.
__device__ __forceinline__ float fast_tanh(float u) {
    float e = exp2f(u * 2.88539008177792681f);          // e^{2u} via v_exp_f32
    return 1.0f - 2.0f * __builtin_amdgcn_rcpf(e + 1.0f);
}

// DPP row-rotate by N within each 16-lane row (full-rate VALU cross-lane).
template <int N>
__device__ __forceinline__ float dpp_ror(float v) {
    return __int_as_float(__builtin_amdgcn_mov_dpp(
        __float_as_int(v), 0x120 | N, 0xF, 0xF, false));
}
// lane-in-32-group xor 16 (BitMode: xor=16,and=0x1F) -- direction-unambiguous.
__device__ __forceinline__ float swz_x16(float v) {
    return __int_as_float(__builtin_amdgcn_ds_swizzle(__float_as_int(v), 0x401F));
}

// ---------------- Pass 1: P[t][row][j] = b[j] + emb[x[t,row]] @ Wx[:,j] ----------------
// (R5 kernel, measured ~66 us) coalesced cooperative row-gather, 16 rows in flight.
__global__ __launch_bounds__(256) void precompute_v5(
        const int* __restrict__ x, const float* __restrict__ emb,
        const float* __restrict__ W_rnn, const float* __restrict__ b_rnn,
        float* __restrict__ P) {
    const int tid = threadIdx.x;
    const int jj  = tid & 31;
    const int l   = tid & 63;
    const int grp = tid >> 5;
    const int g   = (blockIdx.x * 256 + tid) >> 5;
    const int pair0 = g * 16;

    __shared__ float stage[8][16][HH];

    float wx[32];
#pragma unroll
    for (int k = 0; k < 32; ++k) wx[k] = W_rnn[k * HH + jj];
    const float bj = b_rnn[jj];

    const int idxv  = x[pair0 + (jj & 15)];
    const int bbase = (l & 32) * 4;

    float ev[16];
#pragma unroll
    for (int i = 0; i < 16; ++i) {
        int pi = __builtin_amdgcn_ds_bpermute(bbase + 4 * i, idxv);
        ev[i] = emb[(size_t)pi * HH + jj];
    }
#pragma unroll
    for (int i = 0; i < 16; ++i)
        stage[grp][i][jj] = ev[i];

#pragma unroll 4
    for (int i = 0; i < 16; ++i) {
        const float4* sp = (const float4*)&stage[grp][i][0];
        float u0 = bj, u1 = 0.f, u2 = 0.f, u3 = 0.f;
#pragma unroll
        for (int q = 0; q < 8; ++q) {
            float4 e = sp[q];
            u0 = fmaf(e.x, wx[4*q+0], u0);
            u1 = fmaf(e.y, wx[4*q+1], u1);
            u2 = fmaf(e.z, wx[4*q+2], u2);
            u3 = fmaf(e.w, wx[4*q+3], u3);
        }
        P[(size_t)(pair0 + i) * HH + jj] = (u0 + u1) + (u2 + u3);
    }
}

// ---------------- Pass 2: rotation-systolic scan, 2 distinct rows per wave -------------
// Lane l: group g=l&31 (hidden index), half l>>5 picks row 2*blk+(l>>5).  All cross-lane
// ops are 16/32-lane local so the two halves are independent.  Per step:
//   hx = swizzle_xor16(h)                       (other 16-row's h)
//   4+4 rotation streams (row_ror pre-rot 1..3, then ror:4 spines, depth 5 total)
//   32 FMA into 8 accumulators, tree, fast_tanh.
// row_ror direction is probed at runtime (d=+-1) and folded into the weight-load index.
// P feeds from a 16-deep register double ring: coalesced 256 B/wave loads, consumed
// 16..31 steps later (implicit vmcnt long satisfied).
__global__ __launch_bounds__(64) void rnn_seq_v6(
        const float* __restrict__ P, const float* __restrict__ W_rnn,
        const float* __restrict__ W_cls, const float* __restrict__ b_cls,
        float* __restrict__ out) {
    const int l = threadIdx.x;
    const int g = l & 31;
    const int i = g & 15;
    const int R = g & 16;

    // Direction probe: rotate lane-id pattern once; d=+1 if ror:1 pulls from lane i+1.
    int rt = __builtin_amdgcn_mov_dpp(i, 0x121, 0xF, 0xF, false);
    const int d = (rt == ((i + 1) & 15)) ? 1 : -1;

    float wOwn[16], wOpp[16];
#pragma unroll
    for (int o = 0; o < 16; ++o) {
        const int rot = (i + d * o) & 15;
        wOwn[o] = W_rnn[(HH + (R + rot)) * HH + g];
        wOpp[o] = W_rnn[(HH + ((R ^ 16) + rot)) * HH + g];
    }

    // gptr covers rows 2b,2b+1 contiguously: row*HH + g = blk*64 + l.
    const float* gptr = P + (size_t)blockIdx.x * 64 + l;

    float pA[16], pB[16];
#pragma unroll
    for (int q = 0; q < 16; ++q) pA[q] = gptr[(size_t)q * PSTRIDE];

    float h = 0.0f;

    auto step = [&](float p) {
        float hx = swz_x16(h);
        float a0 = h,  a1 = dpp_ror<1>(h),  a2 = dpp_ror<2>(h),  a3 = dpp_ror<3>(h);
        float b0 = hx, b1 = dpp_ror<1>(hx), b2 = dpp_ror<2>(hx), b3 = dpp_ror<3>(hx);
        float u0 = fmaf(a0, wOwn[0], p);
        float u1 = a1 * wOwn[1], u2 = a2 * wOwn[2], u3 = a3 * wOwn[3];
        float u4 = b0 * wOpp[0], u5 = b1 * wOpp[1], u6 = b2 * wOpp[2], u7 = b3 * wOpp[3];
#pragma unroll
        for (int m = 1; m < 4; ++m) {
            a0 = dpp_ror<4>(a0); u0 = fmaf(a0, wOwn[4*m+0], u0);
            a1 = dpp_ror<4>(a1); u1 = fmaf(a1, wOwn[4*m+1], u1);
            a2 = dpp_ror<4>(a2); u2 = fmaf(a2, wOwn[4*m+2], u2);
            a3 = dpp_ror<4>(a3); u3 = fmaf(a3, wOwn[4*m+3], u3);
            b0 = dpp_ror<4>(b0); u4 = fmaf(b0, wOpp[4*m+0], u4);
            b1 = dpp_ror<4>(b1); u5 = fmaf(b1, wOpp[4*m+1], u5);
            b2 = dpp_ror<4>(b2); u6 = fmaf(b2, wOpp[4*m+2], u6);
            b3 = dpp_ror<4>(b3); u7 = fmaf(b3, wOpp[4*m+3], u7);
        }
        float u = ((u0 + u1) + (u2 + u3)) + ((u4 + u5) + (u6 + u7));
        h = fast_tanh(u);
    };

#pragma unroll 1
    for (int e = 0; e < TT / 32; ++e) {
        const int tB = e * 32 + 16;
#pragma unroll
        for (int q = 0; q < 16; ++q) pB[q] = gptr[(size_t)(tB + q) * PSTRIDE];
#pragma unroll
        for (int s = 0; s < 16; ++s) step(pA[s]);

        int tA = e * 32 + 32;
        if (tA > TT - 16) tA = TT - 16;   // redundant tail reload, in-bounds
#pragma unroll
        for (int q = 0; q < 16; ++q) pA[q] = gptr[(size_t)(tA + q) * PSTRIDE];
#pragma unroll
        for (int s = 0; s < 16; ++s) step(pB[s]);
    }

    // Epilogue: y = h @ W_cls + b_cls per half-row (single wave: DS ops wave-ordered).
    __shared__ float hf[64];
    hf[l] = h;
    if (g < 5) {
        float acc = b_cls[g];
#pragma unroll
        for (int k = 0; k < 32; ++k)
            acc = fmaf(hf[(l & 32) + k], W_cls[k * 5 + g], acc);
        out[(blockIdx.x * 2 + (l >> 5)) * 5 + g] = acc;
    }
}

// ---------------- Fallback (fused) for tiny workspace ----------------------------------
__device__ __forceinline__ float rnn_step_fb(const float4 xt[8], const float wx[32],
                                             const float wh[32], float bj,
                                             float* hrow, int lane) {
    float u0 = 0.f, u1 = 0.f, u2 = 0.f, u3 = 0.f;
#pragma unroll
    for (int q = 0; q < 8; ++q) {
        u0 = fmaf(xt[q].x, wx[4*q+0], u0);
        u1 = fmaf(xt[q].y, wx[4*q+1], u1);
        u2 = fmaf(xt[q].z, wx[4*q+2], u2);
        u3 = fmaf(xt[q].w, wx[4*q+3], u3);
    }
    const float4* hp = (const float4*)hrow;
#pragma unroll
    for (int q = 0; q < 8; ++q) {
        float4 hv = hp[q];
        u0 = fmaf(hv.x, wh[4*q+0], u0);
        u1 = fmaf(hv.y, wh[4*q+1], u1);
        u2 = fmaf(hv.z, wh[4*q+2], u2);
        u3 = fmaf(hv.w, wh[4*q+3], u3);
    }
    float hn = fast_tanh(bj + ((u0 + u1) + (u2 + u3)));
    hrow[lane] = hn;
    return hn;
}

__global__ __launch_bounds__(64) void rnn_seq_kernel(
        const int* __restrict__ x, const float* __restrict__ emb,
        const float* __restrict__ W_rnn, const float* __restrict__ b_rnn,
        const float* __restrict__ W_cls, const float* __restrict__ b_cls,
        float* __restrict__ out) {
    const int lane = threadIdx.x & 31;
    const int grp  = threadIdx.x >> 5;
    const int row  = blockIdx.x * 2 + grp;
    __shared__ float hbuf[2][HH];
    float wx[32], wh[32];
#pragma unroll
    for (int k = 0; k < 32; ++k) {
        wx[k] = W_rnn[k * HH + lane];
        wh[k] = W_rnn[(HH + k) * HH + lane];
    }
    const float bj = b_rnn[lane];
    hbuf[grp][lane] = 0.0f;
    float* hrow = &hbuf[grp][0];
    int i1 = x[1 * BB + row];
    float4 xcur[8], xnxt[8];
    {
        int i0 = x[0 * BB + row];
        const float4* ep = (const float4*)(emb + (size_t)i0 * HH);
#pragma unroll
        for (int q = 0; q < 8; ++q) xcur[q] = ep[q];
    }
    for (int t = 0; t < TT; t += 2) {
        int i2 = x[min(t + 2, TT - 1) * BB + row];
        {
            const float4* ep = (const float4*)(emb + (size_t)i1 * HH);
#pragma unroll
            for (int q = 0; q < 8; ++q) xnxt[q] = ep[q];
        }
        rnn_step_fb(xcur, wx, wh, bj, hrow, lane);
        i1 = x[min(t + 3, TT - 1) * BB + row];
        {
            const float4* ep = (const float4*)(emb + (size_t)i2 * HH);
#pragma unroll
            for (int q = 0; q < 8; ++q) xcur[q] = ep[q];
        }
        rnn_step_fb(xnxt, wx, wh, bj, hrow, lane);
    }
    if (lane < 5) {
        float acc = b_cls[lane];
#pragma unroll
        for (int k = 0; k < 32; ++k)
            acc = fmaf(hrow[k], W_cls[k * 5 + lane], acc);
        out[row * 5 + lane] = acc;
    }
}

extern "C" void kernel_launch(void* const* d_in, const int* in_sizes, int n_in,
                              void* d_out, int out_size, void* d_ws, size_t ws_size,
                              hipStream_t stream) {
    const int*   x     = (const int*)d_in[0];
    const float* emb   = (const float*)d_in[1];
    const float* W_rnn = (const float*)d_in[2];
    const float* b_rnn = (const float*)d_in[3];
    const float* W_cls = (const float*)d_in[4];
    const float* b_cls = (const float*)d_in[5];
    float* out = (float*)d_out;

    const size_t need32 = (size_t)NPAIR * HH * 4;   // 128 MiB
    if (ws_size >= need32) {
        float* P = (float*)d_ws;
        const int pre_blocks = NPAIR / (16 * 8);    // 8192 blocks x 256 thr
        precompute_v5<<<pre_blocks, 256, 0, stream>>>(x, emb, W_rnn, b_rnn, P);
        rnn_seq_v6<<<BB / 2, 64, 0, stream>>>(P, W_rnn, W_cls, b_cls, out);
    } else {
        rnn_seq_kernel<<<BB / 2, 64, 0, stream>>>(x, emb, W_rnn, b_rnn, W_cls, b_cls, out);
    }
}

// Round 7
// 539.593 us; speedup vs baseline: 1.4227x; 1.0022x over previous
//
#include <hip/hip_runtime.h>
#include <hip/hip_bf16.h>

#define TT 2048
#define BB 512
#define HH 32
#define NPAIR (TT * BB)
#define PSTRIDE (BB * HH)   // floats per t-slice of P = 16384

// tanh(u) = 1 - 2/(1+e^{2u}); exact at both saturations.
__device__ __forceinline__ float fast_tanh(float u) {
    float e = exp2f(u * 2.88539008177792681f);          // e^{2u} via v_exp_f32
    return 1.0f - 2.0f * __builtin_amdgcn_rcpf(e + 1.0f);
}

// DPP row-rotate by N within each 16-lane row (full-rate VALU cross-lane).
template <int N>
__device__ __forceinline__ float dpp_ror(float v) {
    return __int_as_float(__builtin_amdgcn_mov_dpp(
        __float_as_int(v), 0x120 | N, 0xF, 0xF, false));
}
// lane-in-32-group xor 16 (BitMode: xor=16,and=0x1F) -- direction-unambiguous.
__device__ __forceinline__ float swz_x16(float v) {
    return __int_as_float(__builtin_amdgcn_ds_swizzle(__float_as_int(v), 0x401F));
}

// ---------------- Pass 1: P[t][row][j] = b[j] + emb[x[t,row]] @ Wx[:,j] ----------------
// (measured ~66 us, near its ~45 us gather floor) coalesced cooperative row-gather.
__global__ __launch_bounds__(256) void precompute_v5(
        const int* __restrict__ x, const float* __restrict__ emb,
        const float* __restrict__ W_rnn, const float* __restrict__ b_rnn,
        float* __restrict__ P) {
    const int tid = threadIdx.x;
    const int jj  = tid & 31;
    const int l   = tid & 63;
    const int grp = tid >> 5;
    const int g   = (blockIdx.x * 256 + tid) >> 5;
    const int pair0 = g * 16;

    __shared__ float stage[8][16][HH];

    float wx[32];
#pragma unroll
    for (int k = 0; k < 32; ++k) wx[k] = W_rnn[k * HH + jj];
    const float bj = b_rnn[jj];

    const int idxv  = x[pair0 + (jj & 15)];
    const int bbase = (l & 32) * 4;

    float ev[16];
#pragma unroll
    for (int i = 0; i < 16; ++i) {
        int pi = __builtin_amdgcn_ds_bpermute(bbase + 4 * i, idxv);
        ev[i] = emb[(size_t)pi * HH + jj];
    }
#pragma unroll
    for (int i = 0; i < 16; ++i)
        stage[grp][i][jj] = ev[i];

#pragma unroll 4
    for (int i = 0; i < 16; ++i) {
        const float4* sp = (const float4*)&stage[grp][i][0];
        float u0 = bj, u1 = 0.f, u2 = 0.f, u3 = 0.f;
#pragma unroll
        for (int q = 0; q < 8; ++q) {
            float4 e = sp[q];
            u0 = fmaf(e.x, wx[4*q+0], u0);
            u1 = fmaf(e.y, wx[4*q+1], u1);
            u2 = fmaf(e.z, wx[4*q+2], u2);
            u3 = fmaf(e.w, wx[4*q+3], u3);
        }
        P[(size_t)(pair0 + i) * HH + jj] = (u0 + u1) + (u2 + u3);
    }
}

// ---------------- Pass 2: rotation-systolic scan, 2 distinct rows per wave -------------
// IDENTICAL structure to R6 except __launch_bounds__(64, 1): min 1 wave/EU => VGPR
// budget up to 512, so wOwn/wOpp/pA/pB (64 regs) STAY IN REGISTERS.  R6's VGPR_Count=44
// proves the compiler spilled them to scratch and re-loaded inside the step loop --
// that scratch traffic, not the broadcast mechanism, was the 400+cyc/step stall in
// R2/R4/R6.
__global__ __launch_bounds__(64, 1) void rnn_seq_v7(
        const float* __restrict__ P, const float* __restrict__ W_rnn,
        const float* __restrict__ W_cls, const float* __restrict__ b_cls,
        float* __restrict__ out) {
    const int l = threadIdx.x;
    const int g = l & 31;
    const int i = g & 15;
    const int R = g & 16;

    // Direction probe: rotate lane-id pattern once; d=+1 if ror:1 pulls from lane i+1.
    int rt = __builtin_amdgcn_mov_dpp(i, 0x121, 0xF, 0xF, false);
    const int d = (rt == ((i + 1) & 15)) ? 1 : -1;

    float wOwn[16], wOpp[16];
#pragma unroll
    for (int o = 0; o < 16; ++o) {
        const int rot = (i + d * o) & 15;
        wOwn[o] = W_rnn[(HH + (R + rot)) * HH + g];
        wOpp[o] = W_rnn[(HH + ((R ^ 16) + rot)) * HH + g];
    }

    // gptr covers rows 2b,2b+1 contiguously: row*HH + g = blk*64 + l.
    const float* gptr = P + (size_t)blockIdx.x * 64 + l;

    float pA[16], pB[16];
#pragma unroll
    for (int q = 0; q < 16; ++q) pA[q] = gptr[(size_t)q * PSTRIDE];

    float h = 0.0f;

    auto step = [&](float p) {
        float hx = swz_x16(h);
        float a0 = h,  a1 = dpp_ror<1>(h),  a2 = dpp_ror<2>(h),  a3 = dpp_ror<3>(h);
        float b0 = hx, b1 = dpp_ror<1>(hx), b2 = dpp_ror<2>(hx), b3 = dpp_ror<3>(hx);
        float u0 = fmaf(a0, wOwn[0], p);
        float u1 = a1 * wOwn[1], u2 = a2 * wOwn[2], u3 = a3 * wOwn[3];
        float u4 = b0 * wOpp[0], u5 = b1 * wOpp[1], u6 = b2 * wOpp[2], u7 = b3 * wOpp[3];
#pragma unroll
        for (int m = 1; m < 4; ++m) {
            a0 = dpp_ror<4>(a0); u0 = fmaf(a0, wOwn[4*m+0], u0);
            a1 = dpp_ror<4>(a1); u1 = fmaf(a1, wOwn[4*m+1], u1);
            a2 = dpp_ror<4>(a2); u2 = fmaf(a2, wOwn[4*m+2], u2);
            a3 = dpp_ror<4>(a3); u3 = fmaf(a3, wOwn[4*m+3], u3);
            b0 = dpp_ror<4>(b0); u4 = fmaf(b0, wOpp[4*m+0], u4);
            b1 = dpp_ror<4>(b1); u5 = fmaf(b1, wOpp[4*m+1], u5);
            b2 = dpp_ror<4>(b2); u6 = fmaf(b2, wOpp[4*m+2], u6);
            b3 = dpp_ror<4>(b3); u7 = fmaf(b3, wOpp[4*m+3], u7);
        }
        float u = ((u0 + u1) + (u2 + u3)) + ((u4 + u5) + (u6 + u7));
        h = fast_tanh(u);
    };

#pragma unroll 1
    for (int e = 0; e < TT / 32; ++e) {
        const int tB = e * 32 + 16;
#pragma unroll
        for (int q = 0; q < 16; ++q) pB[q] = gptr[(size_t)(tB + q) * PSTRIDE];
#pragma unroll
        for (int s = 0; s < 16; ++s) step(pA[s]);

        int tA = e * 32 + 32;
        if (tA > TT - 16) tA = TT - 16;   // redundant tail reload, in-bounds
#pragma unroll
        for (int q = 0; q < 16; ++q) pA[q] = gptr[(size_t)(tA + q) * PSTRIDE];
#pragma unroll
        for (int s = 0; s < 16; ++s) step(pB[s]);
    }

    // Epilogue: y = h @ W_cls + b_cls per half-row (single wave: DS ops wave-ordered).
    __shared__ float hf[64];
    hf[l] = h;
    if (g < 5) {
        float acc = b_cls[g];
#pragma unroll
        for (int k = 0; k < 32; ++k)
            acc = fmaf(hf[(l & 32) + k], W_cls[k * 5 + g], acc);
        out[(blockIdx.x * 2 + (l >> 5)) * 5 + g] = acc;
    }
}

// ---------------- Fallback (fused) for tiny workspace ----------------------------------
__device__ __forceinline__ float rnn_step_fb(const float4 xt[8], const float wx[32],
                                             const float wh[32], float bj,
                                             float* hrow, int lane) {
    float u0 = 0.f, u1 = 0.f, u2 = 0.f, u3 = 0.f;
#pragma unroll
    for (int q = 0; q < 8; ++q) {
        u0 = fmaf(xt[q].x, wx[4*q+0], u0);
        u1 = fmaf(xt[q].y, wx[4*q+1], u1);
        u2 = fmaf(xt[q].z, wx[4*q+2], u2);
        u3 = fmaf(xt[q].w, wx[4*q+3], u3);
    }
    const float4* hp = (const float4*)hrow;
#pragma unroll
    for (int q = 0; q < 8; ++q) {
        float4 hv = hp[q];
        u0 = fmaf(hv.x, wh[4*q+0], u0);
        u1 = fmaf(hv.y, wh[4*q+1], u1);
        u2 = fmaf(hv.z, wh[4*q+2], u2);
        u3 = fmaf(hv.w, wh[4*q+3], u3);
    }
    float hn = fast_tanh(bj + ((u0 + u1) + (u2 + u3)));
    hrow[lane] = hn;
    return hn;
}

__global__ __launch_bounds__(64, 1) void rnn_seq_kernel(
        const int* __restrict__ x, const float* __restrict__ emb,
        const float* __restrict__ W_rnn, const float* __restrict__ b_rnn,
        const float* __restrict__ W_cls, const float* __restrict__ b_cls,
        float* __restrict__ out) {
    const int lane = threadIdx.x & 31;
    const int grp  = threadIdx.x >> 5;
    const int row  = blockIdx.x * 2 + grp;
    __shared__ float hbuf[2][HH];
    float wx[32], wh[32];
#pragma unroll
    for (int k = 0; k < 32; ++k) {
        wx[k] = W_rnn[k * HH + lane];
        wh[k] = W_rnn[(HH + k) * HH + lane];
    }
    const float bj = b_rnn[lane];
    hbuf[grp][lane] = 0.0f;
    float* hrow = &hbuf[grp][0];
    int i1 = x[1 * BB + row];
    float4 xcur[8], xnxt[8];
    {
        int i0 = x[0 * BB + row];
        const float4* ep = (const float4*)(emb + (size_t)i0 * HH);
#pragma unroll
        for (int q = 0; q < 8; ++q) xcur[q] = ep[q];
    }
    for (int t = 0; t < TT; t += 2) {
        int i2 = x[min(t + 2, TT - 1) * BB + row];
        {
            const float4* ep = (const float4*)(emb + (size_t)i1 * HH);
#pragma unroll
            for (int q = 0; q < 8; ++q) xnxt[q] = ep[q];
        }
        rnn_step_fb(xcur, wx, wh, bj, hrow, lane);
        i1 = x[min(t + 3, TT - 1) * BB + row];
        {
            const float4* ep = (const float4*)(emb + (size_t)i2 * HH);
#pragma unroll
            for (int q = 0; q < 8; ++q) xcur[q] = ep[q];
        }
        rnn_step_fb(xnxt, wx, wh, bj, hrow, lane);
    }
    if (lane < 5) {
        float acc = b_cls[lane];
#pragma unroll
        for (int k = 0; k < 32; ++k)
            acc = fmaf(hrow[k], W_cls[k * 5 + lane], acc);
        out[row * 5 + lane] = acc;
    }
}

extern "C" void kernel_launch(void* const* d_in, const int* in_sizes, int n_in,
                              void* d_out, int out_size, void* d_ws, size_t ws_size,
                              hipStream_t stream) {
    const int*   x     = (const int*)d_in[0];
    const float* emb   = (const float*)d_in[1];
    const float* W_rnn = (const float*)d_in[2];
    const float* b_rnn = (const float*)d_in[3];
    const float* W_cls = (const float*)d_in[4];
    const float* b_cls = (const float*)d_in[5];
    float* out = (float*)d_out;

    const size_t need32 = (size_t)NPAIR * HH * 4;   // 128 MiB
    if (ws_size >= need32) {
        float* P = (float*)d_ws;
        const int pre_blocks = NPAIR / (16 * 8);    // 8192 blocks x 256 thr
        precompute_v5<<<pre_blocks, 256, 0, stream>>>(x, emb, W_rnn, b_rnn, P);
        rnn_seq_v7<<<BB / 2, 64, 0, stream>>>(P, W_rnn, W_cls, b_cls, out);
    } else {
        rnn_seq_kernel<<<BB / 2, 64, 0, stream>>>(x, emb, W_rnn, b_rnn, W_cls, b_cls, out);
    }
}

// Round 8
// 493.198 us; speedup vs baseline: 1.5566x; 1.0941x over previous
//
#include <hip/hip_runtime.h>
#include <hip/hip_bf16.h>

#define TT 2048
#define BB 512
#define HH 32
#define NPAIR (TT * BB)
#define PSTRIDE (BB * HH)   // floats per t-slice of P = 16384

// Pin a value into a live VGPR at this program point. Defeats the scheduler's
// load-sinking (R6/R7: VGPR_Count=44 proved the batched ring loads were sunk to
// their uses, putting a ~200cyc vmcnt wait in every step's chain).
#define PIN(x) asm volatile("" : "+v"(x))

// tanh(u) = 1 - 2/(1+e^{2u}); exact at both saturations.
__device__ __forceinline__ float fast_tanh(float u) {
    float e = exp2f(u * 2.88539008177792681f);          // e^{2u} via v_exp_f32
    return 1.0f - 2.0f * __builtin_amdgcn_rcpf(e + 1.0f);
}

// DPP row-rotate by N within each 16-lane row (full-rate VALU cross-lane).
template <int N>
__device__ __forceinline__ float dpp_ror(float v) {
    return __int_as_float(__builtin_amdgcn_mov_dpp(
        __float_as_int(v), 0x120 | N, 0xF, 0xF, false));
}

// ---------------- Pass 1: P[t][row][j] = b[j] + emb[x[t,row]] @ Wx[:,j] ----------------
// (measured ~66 us) coalesced cooperative row-gather, 16 rows in flight.
__global__ __launch_bounds__(256) void precompute_v5(
        const int* __restrict__ x, const float* __restrict__ emb,
        const float* __restrict__ W_rnn, const float* __restrict__ b_rnn,
        float* __restrict__ P) {
    const int tid = threadIdx.x;
    const int jj  = tid & 31;
    const int l   = tid & 63;
    const int grp = tid >> 5;
    const int g   = (blockIdx.x * 256 + tid) >> 5;
    const int pair0 = g * 16;

    __shared__ float stage[8][16][HH];

    float wx[32];
#pragma unroll
    for (int k = 0; k < 32; ++k) wx[k] = W_rnn[k * HH + jj];
    const float bj = b_rnn[jj];

    const int idxv  = x[pair0 + (jj & 15)];
    const int bbase = (l & 32) * 4;

    float ev[16];
#pragma unroll
    for (int i = 0; i < 16; ++i) {
        int pi = __builtin_amdgcn_ds_bpermute(bbase + 4 * i, idxv);
        ev[i] = emb[(size_t)pi * HH + jj];
    }
#pragma unroll
    for (int i = 0; i < 16; ++i)
        stage[grp][i][jj] = ev[i];

#pragma unroll 4
    for (int i = 0; i < 16; ++i) {
        const float4* sp = (const float4*)&stage[grp][i][0];
        float u0 = bj, u1 = 0.f, u2 = 0.f, u3 = 0.f;
#pragma unroll
        for (int q = 0; q < 8; ++q) {
            float4 e = sp[q];
            u0 = fmaf(e.x, wx[4*q+0], u0);
            u1 = fmaf(e.y, wx[4*q+1], u1);
            u2 = fmaf(e.z, wx[4*q+2], u2);
            u3 = fmaf(e.w, wx[4*q+3], u3);
        }
        P[(size_t)(pair0 + i) * HH + jj] = (u0 + u1) + (u2 + u3);
    }
}

// ---------------- Pass 2: pure-DPP rotation-systolic scan, 4 rows per wave -------------
// Lane l: i = l&15 (position in 16-lane row), r = l>>4 (row in wave). Lane i of row r
// owns BOTH h[i] (lo) and h[i+16] (hi) => the entire h@Wh dot is row_ror DPP within
// 16-lane rows: 8 rotation streams (lo/hi x pre-rot 0..3), ror:4 spine depth 3.
// ZERO DS / global / readlane ops in the h-chain -- chain is pure VALU (~105 cyc).
// P feeds from an 8-deep double-buffered register ring; PIN() after each batch keeps
// the loads batched & far ahead (waitcnt lands at the pin where data is ~2000 cyc old).
__global__ __launch_bounds__(64, 1) void rnn_seq_v8(
        const float* __restrict__ P, const float* __restrict__ W_rnn,
        const float* __restrict__ W_cls, const float* __restrict__ b_cls,
        float* __restrict__ out) {
    const int l = threadIdx.x;
    const int i = l & 15;
    const int r = l >> 4;

    // Direction probe (validated R6/R7: absmax 0.0): d=+1 if ror:1 pulls from lane i+1.
    int rt = __builtin_amdgcn_mov_dpp(i, 0x121, 0xF, 0xF, false);
    const int d = (rt == ((i + 1) & 15)) ? 1 : -1;

    // Weight tables in rotation order: at offset o, lane i holds h_lo[(i+d*o)&15] and
    // h_hi[(i+d*o)&15]; contributions to u_lo (col i) and u_hi (col i+16).
    float wA[16], wB[16], wC[16], wD[16];
#pragma unroll
    for (int o = 0; o < 16; ++o) {
        const int rot = (i + d * o) & 15;
        wA[o] = W_rnn[(HH + rot) * HH + i];            // h_lo -> u_lo
        wB[o] = W_rnn[(HH + 16 + rot) * HH + i];       // h_hi -> u_lo
        wC[o] = W_rnn[(HH + rot) * HH + (i + 16)];     // h_lo -> u_hi
        wD[o] = W_rnn[(HH + 16 + rot) * HH + (i + 16)];// h_hi -> u_hi
    }
#pragma unroll
    for (int o = 0; o < 16; ++o) { PIN(wA[o]); PIN(wB[o]); PIN(wC[o]); PIN(wD[o]); }

    // Per-slice address: row*HH + i (lo), +16 (hi). row = blk*4 + r.
    const float* gp = P + (size_t)(blockIdx.x * 4 + r) * HH + i;

    float pAl[8], pAh[8], pBl[8], pBh[8];
#pragma unroll
    for (int q = 0; q < 8; ++q) {
        pAl[q] = gp[(size_t)q * PSTRIDE];
        pAh[q] = gp[(size_t)q * PSTRIDE + 16];
    }

    float h_lo = 0.0f, h_hi = 0.0f;

    auto step = [&](float plo, float phi) {
        float a0 = h_lo, a1 = dpp_ror<1>(h_lo), a2 = dpp_ror<2>(h_lo), a3 = dpp_ror<3>(h_lo);
        float b0 = h_hi, b1 = dpp_ror<1>(h_hi), b2 = dpp_ror<2>(h_hi), b3 = dpp_ror<3>(h_hi);
        // m=0 (offsets 0..3)
        float la0 = fmaf(a0, wA[0], plo); la0 = fmaf(b0, wB[0], la0);
        float la1 = a1 * wA[1];           la1 = fmaf(b1, wB[1], la1);
        float la2 = a2 * wA[2];           la2 = fmaf(b2, wB[2], la2);
        float la3 = a3 * wA[3];           la3 = fmaf(b3, wB[3], la3);
        float ha0 = fmaf(a0, wC[0], phi); ha0 = fmaf(b0, wD[0], ha0);
        float ha1 = a1 * wC[1];           ha1 = fmaf(b1, wD[1], ha1);
        float ha2 = a2 * wC[2];           ha2 = fmaf(b2, wD[2], ha2);
        float ha3 = a3 * wC[3];           ha3 = fmaf(b3, wD[3], ha3);
#pragma unroll
        for (int m = 1; m < 4; ++m) {
            a0 = dpp_ror<4>(a0); a1 = dpp_ror<4>(a1);
            a2 = dpp_ror<4>(a2); a3 = dpp_ror<4>(a3);
            b0 = dpp_ror<4>(b0); b1 = dpp_ror<4>(b1);
            b2 = dpp_ror<4>(b2); b3 = dpp_ror<4>(b3);
            la0 = fmaf(a0, wA[4*m+0], la0); la0 = fmaf(b0, wB[4*m+0], la0);
            la1 = fmaf(a1, wA[4*m+1], la1); la1 = fmaf(b1, wB[4*m+1], la1);
            la2 = fmaf(a2, wA[4*m+2], la2); la2 = fmaf(b2, wB[4*m+2], la2);
            la3 = fmaf(a3, wA[4*m+3], la3); la3 = fmaf(b3, wB[4*m+3], la3);
            ha0 = fmaf(a0, wC[4*m+0], ha0); ha0 = fmaf(b0, wD[4*m+0], ha0);
            ha1 = fmaf(a1, wC[4*m+1], ha1); ha1 = fmaf(b1, wD[4*m+1], ha1);
            ha2 = fmaf(a2, wC[4*m+2], ha2); ha2 = fmaf(b2, wD[4*m+2], ha2);
            ha3 = fmaf(a3, wC[4*m+3], ha3); ha3 = fmaf(b3, wD[4*m+3], ha3);
        }
        h_lo = fast_tanh((la0 + la1) + (la2 + la3));
        h_hi = fast_tanh((ha0 + ha1) + (ha2 + ha3));
    };

#pragma unroll 1
    for (int e = 0; e < TT / 16; ++e) {
        const int tB = e * 16 + 8;
#pragma unroll
        for (int q = 0; q < 8; ++q) {
            pBl[q] = gp[(size_t)(tB + q) * PSTRIDE];
            pBh[q] = gp[(size_t)(tB + q) * PSTRIDE + 16];
        }
#pragma unroll
        for (int q = 0; q < 8; ++q) { PIN(pAl[q]); PIN(pAh[q]); }
#pragma unroll
        for (int s = 0; s < 8; ++s) step(pAl[s], pAh[s]);

        int tA = e * 16 + 16;
        if (tA > TT - 8) tA = TT - 8;   // tail reload redundant but in-bounds
#pragma unroll
        for (int q = 0; q < 8; ++q) {
            pAl[q] = gp[(size_t)(tA + q) * PSTRIDE];
            pAh[q] = gp[(size_t)(tA + q) * PSTRIDE + 16];
        }
#pragma unroll
        for (int q = 0; q < 8; ++q) { PIN(pBl[q]); PIN(pBh[q]); }
#pragma unroll
        for (int s = 0; s < 8; ++s) step(pBl[s], pBh[s]);
    }

    // Epilogue: y = h @ W_cls + b_cls for 4 rows (single wave: DS ops wave-ordered).
    __shared__ float hf[4 * HH];
    hf[r * HH + i]      = h_lo;
    hf[r * HH + i + 16] = h_hi;
    if (l < 20) {
        const int rr = l / 5, c = l % 5;
        float acc = b_cls[c];
#pragma unroll
        for (int k = 0; k < 32; ++k)
            acc = fmaf(hf[rr * HH + k], W_cls[k * 5 + c], acc);
        out[(blockIdx.x * 4 + rr) * 5 + c] = acc;
    }
}

// ---------------- Fallback (fused) for tiny workspace ----------------------------------
__device__ __forceinline__ float rnn_step_fb(const float4 xt[8], const float wx[32],
                                             const float wh[32], float bj,
                                             float* hrow, int lane) {
    float u0 = 0.f, u1 = 0.f, u2 = 0.f, u3 = 0.f;
#pragma unroll
    for (int q = 0; q < 8; ++q) {
        u0 = fmaf(xt[q].x, wx[4*q+0], u0);
        u1 = fmaf(xt[q].y, wx[4*q+1], u1);
        u2 = fmaf(xt[q].z, wx[4*q+2], u2);
        u3 = fmaf(xt[q].w, wx[4*q+3], u3);
    }
    const float4* hp = (const float4*)hrow;
#pragma unroll
    for (int q = 0; q < 8; ++q) {
        float4 hv = hp[q];
        u0 = fmaf(hv.x, wh[4*q+0], u0);
        u1 = fmaf(hv.y, wh[4*q+1], u1);
        u2 = fmaf(hv.z, wh[4*q+2], u2);
        u3 = fmaf(hv.w, wh[4*q+3], u3);
    }
    float hn = fast_tanh(bj + ((u0 + u1) + (u2 + u3)));
    hrow[lane] = hn;
    return hn;
}

__global__ __launch_bounds__(64, 1) void rnn_seq_kernel(
        const int* __restrict__ x, const float* __restrict__ emb,
        const float* __restrict__ W_rnn, const float* __restrict__ b_rnn,
        const float* __restrict__ W_cls, const float* __restrict__ b_cls,
        float* __restrict__ out) {
    const int lane = threadIdx.x & 31;
    const int grp  = threadIdx.x >> 5;
    const int row  = blockIdx.x * 2 + grp;
    __shared__ float hbuf[2][HH];
    float wx[32], wh[32];
#pragma unroll
    for (int k = 0; k < 32; ++k) {
        wx[k] = W_rnn[k * HH + lane];
        wh[k] = W_rnn[(HH + k) * HH + lane];
    }
    const float bj = b_rnn[lane];
    hbuf[grp][lane] = 0.0f;
    float* hrow = &hbuf[grp][0];
    int i1 = x[1 * BB + row];
    float4 xcur[8], xnxt[8];
    {
        int i0 = x[0 * BB + row];
        const float4* ep = (const float4*)(emb + (size_t)i0 * HH);
#pragma unroll
        for (int q = 0; q < 8; ++q) xcur[q] = ep[q];
    }
    for (int t = 0; t < TT; t += 2) {
        int i2 = x[min(t + 2, TT - 1) * BB + row];
        {
            const float4* ep = (const float4*)(emb + (size_t)i1 * HH);
#pragma unroll
            for (int q = 0; q < 8; ++q) xnxt[q] = ep[q];
        }
        rnn_step_fb(xcur, wx, wh, bj, hrow, lane);
        i1 = x[min(t + 3, TT - 1) * BB + row];
        {
            const float4* ep = (const float4*)(emb + (size_t)i2 * HH);
#pragma unroll
            for (int q = 0; q < 8; ++q) xcur[q] = ep[q];
        }
        rnn_step_fb(xnxt, wx, wh, bj, hrow, lane);
    }
    if (lane < 5) {
        float acc = b_cls[lane];
#pragma unroll
        for (int k = 0; k < 32; ++k)
            acc = fmaf(hrow[k], W_cls[k * 5 + lane], acc);
        out[row * 5 + lane] = acc;
    }
}

extern "C" void kernel_launch(void* const* d_in, const int* in_sizes, int n_in,
                              void* d_out, int out_size, void* d_ws, size_t ws_size,
                              hipStream_t stream) {
    const int*   x     = (const int*)d_in[0];
    const float* emb   = (const float*)d_in[1];
    const float* W_rnn = (const float*)d_in[2];
    const float* b_rnn = (const float*)d_in[3];
    const float* W_cls = (const float*)d_in[4];
    const float* b_cls = (const float*)d_in[5];
    float* out = (float*)d_out;

    const size_t need32 = (size_t)NPAIR * HH * 4;   // 128 MiB
    if (ws_size >= need32) {
        float* P = (float*)d_ws;
        const int pre_blocks = NPAIR / (16 * 8);    // 8192 blocks x 256 thr
        precompute_v5<<<pre_blocks, 256, 0, stream>>>(x, emb, W_rnn, b_rnn, P);
        rnn_seq_v8<<<BB / 4, 64, 0, stream>>>(P, W_rnn, W_cls, b_cls, out);
    } else {
        rnn_seq_kernel<<<BB / 2, 64, 0, stream>>>(x, emb, W_rnn, b_rnn, W_cls, b_cls, out);
    }
}

// Round 9
// 418.642 us; speedup vs baseline: 1.8338x; 1.1781x over previous
//
#include <hip/hip_runtime.h>
#include <hip/hip_bf16.h>

#define TT 2048
#define BB 512
#define HH 32
#define NPAIR (TT * BB)
#define PSTRIDE (BB * HH)   // floats per t-slice of P = 16384

// Pin a value into a live VGPR at this point (defeats load-sinking; R8: VGPR 44->88).
#define PIN(x) asm volatile("" : "+v"(x))

// tanh(u) = 1 - 2/(1+e^{2u}); exact at both saturations.
__device__ __forceinline__ float fast_tanh(float u) {
    float e = exp2f(u * 2.88539008177792681f);          // e^{2u} via v_exp_f32
    return 1.0f - 2.0f * __builtin_amdgcn_rcpf(e + 1.0f);
}

// DPP row-rotate by N within each 16-lane row.
template <int N>
__device__ __forceinline__ float dpp_ror(float v) {
    return __int_as_float(__builtin_amdgcn_mov_dpp(
        __float_as_int(v), 0x120 | N, 0xF, 0xF, false));
}
// lane xor 16 within each 32-lane group (BitMode: xor=16, and=0x1F).
__device__ __forceinline__ float swz_x16(float v) {
    return __int_as_float(__builtin_amdgcn_ds_swizzle(__float_as_int(v), 0x401F));
}

// ---------------- Pass 1: P[t][row][j] = b[j] + emb[x[t,row]] @ Wx[:,j] ----------------
// (measured ~66 us) coalesced cooperative row-gather, 16 rows in flight.
__global__ __launch_bounds__(256) void precompute_v5(
        const int* __restrict__ x, const float* __restrict__ emb,
        const float* __restrict__ W_rnn, const float* __restrict__ b_rnn,
        float* __restrict__ P) {
    const int tid = threadIdx.x;
    const int jj  = tid & 31;
    const int l   = tid & 63;
    const int grp = tid >> 5;
    const int g   = (blockIdx.x * 256 + tid) >> 5;
    const int pair0 = g * 16;

    __shared__ float stage[8][16][HH];

    float wx[32];
#pragma unroll
    for (int k = 0; k < 32; ++k) wx[k] = W_rnn[k * HH + jj];
    const float bj = b_rnn[jj];

    const int idxv  = x[pair0 + (jj & 15)];
    const int bbase = (l & 32) * 4;

    float ev[16];
#pragma unroll
    for (int i = 0; i < 16; ++i) {
        int pi = __builtin_amdgcn_ds_bpermute(bbase + 4 * i, idxv);
        ev[i] = emb[(size_t)pi * HH + jj];
    }
#pragma unroll
    for (int i = 0; i < 16; ++i)
        stage[grp][i][jj] = ev[i];

#pragma unroll 4
    for (int i = 0; i < 16; ++i) {
        const float4* sp = (const float4*)&stage[grp][i][0];
        float u0 = bj, u1 = 0.f, u2 = 0.f, u3 = 0.f;
#pragma unroll
        for (int q = 0; q < 8; ++q) {
            float4 e = sp[q];
            u0 = fmaf(e.x, wx[4*q+0], u0);
            u1 = fmaf(e.y, wx[4*q+1], u1);
            u2 = fmaf(e.z, wx[4*q+2], u2);
            u3 = fmaf(e.w, wx[4*q+3], u3);
        }
        P[(size_t)(pair0 + i) * HH + jj] = (u0 + u1) + (u2 + u3);
    }
}

// ---------------- Pass 2: k-split scan, 2 rows/wave, 256 blocks (all CUs) --------------
// Lane l: r=l>>5 (batch row in block), q=(l>>4)&1 (k-half), i=l&15.  Lane owns
// h[q*16+i].  One shared 15-DPP rotation stream (stored in rot[16]) feeds both:
//   keep = sum_o h[q*16+rot(o)] * Wh[q*16+rot(o)][q*16+i]      (own k-half, own j)
//   send = sum_o h[q*16+rot(o)] * Wh[q*16+rot(o)][(q^1)*16+i]  (own k-half, partner j)
// One ds_swizzle xor16 swaps send partials between the q-halves (issued before the
// keep tree so its latency hides); u = keep + recv + p; ONE tanh per lane; next
// h[q*16+i] = tanh(u) stays in-lane -- no post-tanh exchange.
__global__ __launch_bounds__(64, 1) void rnn_seq_v9(
        const float* __restrict__ P, const float* __restrict__ W_rnn,
        const float* __restrict__ W_cls, const float* __restrict__ b_cls,
        float* __restrict__ out) {
    const int l = threadIdx.x;
    const int i = l & 15;
    const int q = (l >> 4) & 1;

    // Direction probe (validated R6-R8: absmax 0.0): d=+1 if ror:1 pulls from lane i+1.
    int rt = __builtin_amdgcn_mov_dpp(i, 0x121, 0xF, 0xF, false);
    const int d = (rt == ((i + 1) & 15)) ? 1 : -1;

    // Weights in rotation order; j preselected per lane (no per-step cndmask).
    float wKeep[16], wSend[16];
#pragma unroll
    for (int o = 0; o < 16; ++o) {
        const int k = q * 16 + ((i + d * o) & 15);     // h index at offset o
        wKeep[o] = W_rnn[(HH + k) * HH + (q * 16 + i)];
        wSend[o] = W_rnn[(HH + k) * HH + ((q ^ 1) * 16 + i)];
    }
#pragma unroll
    for (int o = 0; o < 16; ++o) { PIN(wKeep[o]); PIN(wSend[o]); }

    // p address: row*HH + q*16 + i = blk*64 + l (contiguous 256B per wave-load).
    const float* gp = P + (size_t)blockIdx.x * 64 + l;

    float pA[8], pB[8];
#pragma unroll
    for (int t = 0; t < 8; ++t) pA[t] = gp[(size_t)t * PSTRIDE];

    float h = 0.0f;

    auto step = [&](float p) {
        // Shared rotation stream -> rot[0..15] (15 DPP total).
        float rot[16];
        rot[0] = h;
        rot[1] = dpp_ror<1>(h);
        rot[2] = dpp_ror<2>(h);
        rot[3] = dpp_ror<3>(h);
#pragma unroll
        for (int m = 1; m < 4; ++m) {
            rot[4*m+0] = dpp_ror<4>(rot[4*m-4]);
            rot[4*m+1] = dpp_ror<4>(rot[4*m-3]);
            rot[4*m+2] = dpp_ror<4>(rot[4*m-2]);
            rot[4*m+3] = dpp_ror<4>(rot[4*m-1]);
        }
        // Send partial first (4 accs, depth 4), then swizzle it out early.
        float s0 = rot[0] * wSend[0], s1 = rot[1] * wSend[1];
        float s2 = rot[2] * wSend[2], s3 = rot[3] * wSend[3];
#pragma unroll
        for (int m = 1; m < 4; ++m) {
            s0 = fmaf(rot[4*m+0], wSend[4*m+0], s0);
            s1 = fmaf(rot[4*m+1], wSend[4*m+1], s1);
            s2 = fmaf(rot[4*m+2], wSend[4*m+2], s2);
            s3 = fmaf(rot[4*m+3], wSend[4*m+3], s3);
        }
        float send = (s0 + s1) + (s2 + s3);
        float recv = swz_x16(send);                 // latency hidden under keep FMAs
        // Keep partial (4 accs, depth 4) from the stored rotations.
        float k0 = fmaf(rot[0], wKeep[0], p), k1 = rot[1] * wKeep[1];
        float k2 = rot[2] * wKeep[2],         k3 = rot[3] * wKeep[3];
#pragma unroll
        for (int m = 1; m < 4; ++m) {
            k0 = fmaf(rot[4*m+0], wKeep[4*m+0], k0);
            k1 = fmaf(rot[4*m+1], wKeep[4*m+1], k1);
            k2 = fmaf(rot[4*m+2], wKeep[4*m+2], k2);
            k3 = fmaf(rot[4*m+3], wKeep[4*m+3], k3);
        }
        float u = ((k0 + k1) + (k2 + k3)) + recv;
        h = fast_tanh(u);
    };

#pragma unroll 1
    for (int e = 0; e < TT / 16; ++e) {
        const int tB = e * 16 + 8;
#pragma unroll
        for (int t = 0; t < 8; ++t) pB[t] = gp[(size_t)(tB + t) * PSTRIDE];
#pragma unroll
        for (int t = 0; t < 8; ++t) PIN(pA[t]);
#pragma unroll
        for (int s = 0; s < 8; ++s) step(pA[s]);

        int tA = e * 16 + 16;
        if (tA > TT - 8) tA = TT - 8;   // tail reload redundant but in-bounds
#pragma unroll
        for (int t = 0; t < 8; ++t) pA[t] = gp[(size_t)(tA + t) * PSTRIDE];
#pragma unroll
        for (int t = 0; t < 8; ++t) PIN(pB[t]);
#pragma unroll
        for (int s = 0; s < 8; ++s) step(pB[s]);
    }

    // Epilogue: hf[l] = h lands exactly at hf[r*32 + q*16 + i]; 10 lanes store y.
    __shared__ float hf[64];
    hf[l] = h;
    if (l < 10) {
        const int rr = l / 5, c = l % 5;
        float acc = b_cls[c];
#pragma unroll
        for (int k = 0; k < 32; ++k)
            acc = fmaf(hf[rr * 32 + k], W_cls[k * 5 + c], acc);
        out[(blockIdx.x * 2 + rr) * 5 + c] = acc;
    }
}

// ---------------- Fallback (fused) for tiny workspace ----------------------------------
__device__ __forceinline__ float rnn_step_fb(const float4 xt[8], const float wx[32],
                                             const float wh[32], float bj,
                                             float* hrow, int lane) {
    float u0 = 0.f, u1 = 0.f, u2 = 0.f, u3 = 0.f;
#pragma unroll
    for (int q = 0; q < 8; ++q) {
        u0 = fmaf(xt[q].x, wx[4*q+0], u0);
        u1 = fmaf(xt[q].y, wx[4*q+1], u1);
        u2 = fmaf(xt[q].z, wx[4*q+2], u2);
        u3 = fmaf(xt[q].w, wx[4*q+3], u3);
    }
    const float4* hp = (const float4*)hrow;
#pragma unroll
    for (int q = 0; q < 8; ++q) {
        float4 hv = hp[q];
        u0 = fmaf(hv.x, wh[4*q+0], u0);
        u1 = fmaf(hv.y, wh[4*q+1], u1);
        u2 = fmaf(hv.z, wh[4*q+2], u2);
        u3 = fmaf(hv.w, wh[4*q+3], u3);
    }
    float hn = fast_tanh(bj + ((u0 + u1) + (u2 + u3)));
    hrow[lane] = hn;
    return hn;
}

__global__ __launch_bounds__(64, 1) void rnn_seq_kernel(
        const int* __restrict__ x, const float* __restrict__ emb,
        const float* __restrict__ W_rnn, const float* __restrict__ b_rnn,
        const float* __restrict__ W_cls, const float* __restrict__ b_cls,
        float* __restrict__ out) {
    const int lane = threadIdx.x & 31;
    const int grp  = threadIdx.x >> 5;
    const int row  = blockIdx.x * 2 + grp;
    __shared__ float hbuf[2][HH];
    float wx[32], wh[32];
#pragma unroll
    for (int k = 0; k < 32; ++k) {
        wx[k] = W_rnn[k * HH + lane];
        wh[k] = W_rnn[(HH + k) * HH + lane];
    }
    const float bj = b_rnn[lane];
    hbuf[grp][lane] = 0.0f;
    float* hrow = &hbuf[grp][0];
    int i1 = x[1 * BB + row];
    float4 xcur[8], xnxt[8];
    {
        int i0 = x[0 * BB + row];
        const float4* ep = (const float4*)(emb + (size_t)i0 * HH);
#pragma unroll
        for (int q = 0; q < 8; ++q) xcur[q] = ep[q];
    }
    for (int t = 0; t < TT; t += 2) {
        int i2 = x[min(t + 2, TT - 1) * BB + row];
        {
            const float4* ep = (const float4*)(emb + (size_t)i1 * HH);
#pragma unroll
            for (int q = 0; q < 8; ++q) xnxt[q] = ep[q];
        }
        rnn_step_fb(xcur, wx, wh, bj, hrow, lane);
        i1 = x[min(t + 3, TT - 1) * BB + row];
        {
            const float4* ep = (const float4*)(emb + (size_t)i2 * HH);
#pragma unroll
            for (int q = 0; q < 8; ++q) xcur[q] = ep[q];
        }
        rnn_step_fb(xnxt, wx, wh, bj, hrow, lane);
    }
    if (lane < 5) {
        float acc = b_cls[lane];
#pragma unroll
        for (int k = 0; k < 32; ++k)
            acc = fmaf(hrow[k], W_cls[k * 5 + lane], acc);
        out[row * 5 + lane] = acc;
    }
}

extern "C" void kernel_launch(void* const* d_in, const int* in_sizes, int n_in,
                              void* d_out, int out_size, void* d_ws, size_t ws_size,
                              hipStream_t stream) {
    const int*   x     = (const int*)d_in[0];
    const float* emb   = (const float*)d_in[1];
    const float* W_rnn = (const float*)d_in[2];
    const float* b_rnn = (const float*)d_in[3];
    const float* W_cls = (const float*)d_in[4];
    const float* b_cls = (const float*)d_in[5];
    float* out = (float*)d_out;

    const size_t need32 = (size_t)NPAIR * HH * 4;   // 128 MiB
    if (ws_size >= need32) {
        float* P = (float*)d_ws;
        const int pre_blocks = NPAIR / (16 * 8);    // 8192 blocks x 256 thr
        precompute_v5<<<pre_blocks, 256, 0, stream>>>(x, emb, W_rnn, b_rnn, P);
        rnn_seq_v9<<<BB / 2, 64, 0, stream>>>(P, W_rnn, W_cls, b_cls, out);
    } else {
        rnn_seq_kernel<<<BB / 2, 64, 0, stream>>>(x, emb, W_rnn, b_rnn, W_cls, b_cls, out);
    }
}

// Round 10
// 415.465 us; speedup vs baseline: 1.8478x; 1.0076x over previous
//
#include <hip/hip_runtime.h>
#include <hip/hip_bf16.h>

#define TT 2048
#define BB 512
#define HH 32
#define NPAIR (TT * BB)
#define PSTRIDE (BB * HH)   // floats per t-slice of P = 16384

// Laundering barrier: forces x to be a materialized register HERE, and the memory
// clobber makes load-rematerialization across it illegal (the asm may have written
// the source address). R9's plain "+v" pin stopped sinking but NOT remat-at-use:
// VGPR_Count=44 proved the 32 weight loads were re-executed inside the step loop
// (~70 extra issue cyc/step). This closes that hole.
#define LAUNDER(x) asm volatile("" : "+v"(x) :: "memory")

// tanh(u) = 1 - 2/(1+e^{2u}); exact at both saturations.
__device__ __forceinline__ float fast_tanh(float u) {
    float e = exp2f(u * 2.88539008177792681f);          // e^{2u} via v_exp_f32
    return 1.0f - 2.0f * __builtin_amdgcn_rcpf(e + 1.0f);
}

// DPP row-rotate by N within each 16-lane row.
template <int N>
__device__ __forceinline__ float dpp_ror(float v) {
    return __int_as_float(__builtin_amdgcn_mov_dpp(
        __float_as_int(v), 0x120 | N, 0xF, 0xF, false));
}
// lane xor 16 within each 32-lane group (BitMode: xor=16, and=0x1F).
__device__ __forceinline__ float swz_x16(float v) {
    return __int_as_float(__builtin_amdgcn_ds_swizzle(__float_as_int(v), 0x401F));
}

// ---------------- Pass 1: P[t][row][j] = b[j] + emb[x[t,row]] @ Wx[:,j] ----------------
// (measured ~66 us) coalesced cooperative row-gather, 16 rows in flight.
__global__ __launch_bounds__(256) void precompute_v5(
        const int* __restrict__ x, const float* __restrict__ emb,
        const float* __restrict__ W_rnn, const float* __restrict__ b_rnn,
        float* __restrict__ P) {
    const int tid = threadIdx.x;
    const int jj  = tid & 31;
    const int l   = tid & 63;
    const int grp = tid >> 5;
    const int g   = (blockIdx.x * 256 + tid) >> 5;
    const int pair0 = g * 16;

    __shared__ float stage[8][16][HH];

    float wx[32];
#pragma unroll
    for (int k = 0; k < 32; ++k) wx[k] = W_rnn[k * HH + jj];
    const float bj = b_rnn[jj];

    const int idxv  = x[pair0 + (jj & 15)];
    const int bbase = (l & 32) * 4;

    float ev[16];
#pragma unroll
    for (int i = 0; i < 16; ++i) {
        int pi = __builtin_amdgcn_ds_bpermute(bbase + 4 * i, idxv);
        ev[i] = emb[(size_t)pi * HH + jj];
    }
#pragma unroll
    for (int i = 0; i < 16; ++i)
        stage[grp][i][jj] = ev[i];

#pragma unroll 4
    for (int i = 0; i < 16; ++i) {
        const float4* sp = (const float4*)&stage[grp][i][0];
        float u0 = bj, u1 = 0.f, u2 = 0.f, u3 = 0.f;
#pragma unroll
        for (int q = 0; q < 8; ++q) {
            float4 e = sp[q];
            u0 = fmaf(e.x, wx[4*q+0], u0);
            u1 = fmaf(e.y, wx[4*q+1], u1);
            u2 = fmaf(e.z, wx[4*q+2], u2);
            u3 = fmaf(e.w, wx[4*q+3], u3);
        }
        P[(size_t)(pair0 + i) * HH + jj] = (u0 + u1) + (u2 + u3);
    }
}

// ---------------- Pass 2: k-split scan (R9 structure, laundered operands) --------------
// Lane l: r=l>>5 (row), q=(l>>4)&1 (k-half), i=l&15. Lane owns h[q*16+i].
// One 15-DPP rotation stream feeds keep- and send-partials; ONE ds_swizzle xor16
// exchanges the k-half partials (latency hidden under the keep tree); one tanh/lane.
__global__ __launch_bounds__(64, 1) void rnn_seq_v10(
        const float* __restrict__ P, const float* __restrict__ W_rnn,
        const float* __restrict__ W_cls, const float* __restrict__ b_cls,
        float* __restrict__ out) {
    const int l = threadIdx.x;
    const int i = l & 15;
    const int q = (l >> 4) & 1;

    // Direction probe (validated R6-R9: absmax 0.0).
    int rt = __builtin_amdgcn_mov_dpp(i, 0x121, 0xF, 0xF, false);
    const int d = (rt == ((i + 1) & 15)) ? 1 : -1;

    // Weights in rotation order; laundered so the loop consumes register values
    // (no remat, no sink).
    float wKeep[16], wSend[16];
#pragma unroll
    for (int o = 0; o < 16; ++o) {
        const int k = q * 16 + ((i + d * o) & 15);
        wKeep[o] = W_rnn[(HH + k) * HH + (q * 16 + i)];
        wSend[o] = W_rnn[(HH + k) * HH + ((q ^ 1) * 16 + i)];
    }
#pragma unroll
    for (int o = 0; o < 16; ++o) { LAUNDER(wKeep[o]); LAUNDER(wSend[o]); }

    // p address: row*HH + q*16 + i = blk*64 + l (contiguous 256B per wave-load).
    const float* gp = P + (size_t)blockIdx.x * 64 + l;

    float pA[8], pB[8];
#pragma unroll
    for (int t = 0; t < 8; ++t) pA[t] = gp[(size_t)t * PSTRIDE];

    float h = 0.0f;

    auto step = [&](float p) {
        float rot[16];
        rot[0] = h;
        rot[1] = dpp_ror<1>(h);
        rot[2] = dpp_ror<2>(h);
        rot[3] = dpp_ror<3>(h);
#pragma unroll
        for (int m = 1; m < 4; ++m) {
            rot[4*m+0] = dpp_ror<4>(rot[4*m-4]);
            rot[4*m+1] = dpp_ror<4>(rot[4*m-3]);
            rot[4*m+2] = dpp_ror<4>(rot[4*m-2]);
            rot[4*m+3] = dpp_ror<4>(rot[4*m-1]);
        }
        // Send partial first, swizzle it out early (latency hides under keep tree).
        float s0 = rot[0] * wSend[0], s1 = rot[1] * wSend[1];
        float s2 = rot[2] * wSend[2], s3 = rot[3] * wSend[3];
#pragma unroll
        for (int m = 1; m < 4; ++m) {
            s0 = fmaf(rot[4*m+0], wSend[4*m+0], s0);
            s1 = fmaf(rot[4*m+1], wSend[4*m+1], s1);
            s2 = fmaf(rot[4*m+2], wSend[4*m+2], s2);
            s3 = fmaf(rot[4*m+3], wSend[4*m+3], s3);
        }
        float send = (s0 + s1) + (s2 + s3);
        float recv = swz_x16(send);
        float k0 = fmaf(rot[0], wKeep[0], p), k1 = rot[1] * wKeep[1];
        float k2 = rot[2] * wKeep[2],         k3 = rot[3] * wKeep[3];
#pragma unroll
        for (int m = 1; m < 4; ++m) {
            k0 = fmaf(rot[4*m+0], wKeep[4*m+0], k0);
            k1 = fmaf(rot[4*m+1], wKeep[4*m+1], k1);
            k2 = fmaf(rot[4*m+2], wKeep[4*m+2], k2);
            k3 = fmaf(rot[4*m+3], wKeep[4*m+3], k3);
        }
        float u = ((k0 + k1) + (k2 + k3)) + recv;
        h = fast_tanh(u);
    };

#pragma unroll 1
    for (int e = 0; e < TT / 16; ++e) {
        const int tB = e * 16 + 8;
        // Issue next-half loads, THEN launder the ready half (its loads are 8 steps
        // old => the inserted vmcnt is ~free); loads can't sink across the launder.
#pragma unroll
        for (int t = 0; t < 8; ++t) pB[t] = gp[(size_t)(tB + t) * PSTRIDE];
#pragma unroll
        for (int t = 0; t < 8; ++t) LAUNDER(pA[t]);
#pragma unroll
        for (int s = 0; s < 8; ++s) step(pA[s]);

        int tA = e * 16 + 16;
        if (tA > TT - 8) tA = TT - 8;   // tail reload redundant but in-bounds
#pragma unroll
        for (int t = 0; t < 8; ++t) pA[t] = gp[(size_t)(tA + t) * PSTRIDE];
#pragma unroll
        for (int t = 0; t < 8; ++t) LAUNDER(pB[t]);
#pragma unroll
        for (int s = 0; s < 8; ++s) step(pB[s]);
    }

    // Epilogue: hf[l] = h lands exactly at hf[r*32 + q*16 + i]; 10 lanes store y.
    __shared__ float hf[64];
    hf[l] = h;
    if (l < 10) {
        const int rr = l / 5, c = l % 5;
        float acc = b_cls[c];
#pragma unroll
        for (int k = 0; k < 32; ++k)
            acc = fmaf(hf[rr * 32 + k], W_cls[k * 5 + c], acc);
        out[(blockIdx.x * 2 + rr) * 5 + c] = acc;
    }
}

// ---------------- Fallback (fused) for tiny workspace ----------------------------------
__device__ __forceinline__ float rnn_step_fb(const float4 xt[8], const float wx[32],
                                             const float wh[32], float bj,
                                             float* hrow, int lane) {
    float u0 = 0.f, u1 = 0.f, u2 = 0.f, u3 = 0.f;
#pragma unroll
    for (int q = 0; q < 8; ++q) {
        u0 = fmaf(xt[q].x, wx[4*q+0], u0);
        u1 = fmaf(xt[q].y, wx[4*q+1], u1);
        u2 = fmaf(xt[q].z, wx[4*q+2], u2);
        u3 = fmaf(xt[q].w, wx[4*q+3], u3);
    }
    const float4* hp = (const float4*)hrow;
#pragma unroll
    for (int q = 0; q < 8; ++q) {
        float4 hv = hp[q];
        u0 = fmaf(hv.x, wh[4*q+0], u0);
        u1 = fmaf(hv.y, wh[4*q+1], u1);
        u2 = fmaf(hv.z, wh[4*q+2], u2);
        u3 = fmaf(hv.w, wh[4*q+3], u3);
    }
    float hn = fast_tanh(bj + ((u0 + u1) + (u2 + u3)));
    hrow[lane] = hn;
    return hn;
}

__global__ __launch_bounds__(64, 1) void rnn_seq_kernel(
        const int* __restrict__ x, const float* __restrict__ emb,
        const float* __restrict__ W_rnn, const float* __restrict__ b_rnn,
        const float* __restrict__ W_cls, const float* __restrict__ b_cls,
        float* __restrict__ out) {
    const int lane = threadIdx.x & 31;
    const int grp  = threadIdx.x >> 5;
    const int row  = blockIdx.x * 2 + grp;
    __shared__ float hbuf[2][HH];
    float wx[32], wh[32];
#pragma unroll
    for (int k = 0; k < 32; ++k) {
        wx[k] = W_rnn[k * HH + lane];
        wh[k] = W_rnn[(HH + k) * HH + lane];
    }
    const float bj = b_rnn[lane];
    hbuf[grp][lane] = 0.0f;
    float* hrow = &hbuf[grp][0];
    int i1 = x[1 * BB + row];
    float4 xcur[8], xnxt[8];
    {
        int i0 = x[0 * BB + row];
        const float4* ep = (const float4*)(emb + (size_t)i0 * HH);
#pragma unroll
        for (int q = 0; q < 8; ++q) xcur[q] = ep[q];
    }
    for (int t = 0; t < TT; t += 2) {
        int i2 = x[min(t + 2, TT - 1) * BB + row];
        {
            const float4* ep = (const float4*)(emb + (size_t)i1 * HH);
#pragma unroll
            for (int q = 0; q < 8; ++q) xnxt[q] = ep[q];
        }
        rnn_step_fb(xcur, wx, wh, bj, hrow, lane);
        i1 = x[min(t + 3, TT - 1) * BB + row];
        {
            const float4* ep = (const float4*)(emb + (size_t)i2 * HH);
#pragma unroll
            for (int q = 0; q < 8; ++q) xcur[q] = ep[q];
        }
        rnn_step_fb(xnxt, wx, wh, bj, hrow, lane);
    }
    if (lane < 5) {
        float acc = b_cls[lane];
#pragma unroll
        for (int k = 0; k < 32; ++k)
            acc = fmaf(hrow[k], W_cls[k * 5 + lane], acc);
        out[row * 5 + lane] = acc;
    }
}

extern "C" void kernel_launch(void* const* d_in, const int* in_sizes, int n_in,
                              void* d_out, int out_size, void* d_ws, size_t ws_size,
                              hipStream_t stream) {
    const int*   x     = (const int*)d_in[0];
    const float* emb   = (const float*)d_in[1];
    const float* W_rnn = (const float*)d_in[2];
    const float* b_rnn = (const float*)d_in[3];
    const float* W_cls = (const float*)d_in[4];
    const float* b_cls = (const float*)d_in[5];
    float* out = (float*)d_out;

    const size_t need32 = (size_t)NPAIR * HH * 4;   // 128 MiB
    if (ws_size >= need32) {
        float* P = (float*)d_ws;
        const int pre_blocks = NPAIR / (16 * 8);    // 8192 blocks x 256 thr
        precompute_v5<<<pre_blocks, 256, 0, stream>>>(x, emb, W_rnn, b_rnn, P);
        rnn_seq_v10<<<BB / 2, 64, 0, stream>>>(P, W_rnn, W_cls, b_cls, out);
    } else {
        rnn_seq_kernel<<<BB / 2, 64, 0, stream>>>(x, emb, W_rnn, b_rnn, W_cls, b_cls, out);
    }
}

// Round 11
// 399.436 us; speedup vs baseline: 1.9219x; 1.0401x over previous
//
#include <hip/hip_runtime.h>
#include <hip/hip_bf16.h>

#define TT 2048
#define BB 512
#define HH 32
#define NPAIR (TT * BB)
#define PSTRIDE (BB * HH)   // elements per t-slice of P = 16384

// Pin a value into a live VGPR at this point (R9-exact: no memory clobber --
// the clobber variant (R10) regressed 308->317).
#define PIN(x) asm volatile("" : "+v"(x))

// tanh(u) = 1 - 2/(1+e^{2u}); exact at both saturations.
__device__ __forceinline__ float fast_tanh(float u) {
    float e = exp2f(u * 2.88539008177792681f);          // e^{2u} via v_exp_f32
    return fmaf(__builtin_amdgcn_rcpf(e + 1.0f), -2.0f, 1.0f);
}

// DPP row-rotate by N within each 16-lane row.
template <int N>
__device__ __forceinline__ float dpp_ror(float v) {
    return __int_as_float(__builtin_amdgcn_mov_dpp(
        __float_as_int(v), 0x120 | N, 0xF, 0xF, false));
}
// lane xor 16 within each 32-lane group (BitMode: xor=16, and=0x1F).
__device__ __forceinline__ float swz_x16(float v) {
    return __int_as_float(__builtin_amdgcn_ds_swizzle(__float_as_int(v), 0x401F));
}

// ---------------- Pass 1: P[t][row][j] = b[j] + emb[x[t,row]] @ Wx[:,j]  (bf16 out) ----
// Coalesced cooperative row-gather, 16 rows in flight. bf16 P halves the write
// traffic (128->64 MiB): the fp32 version measured ~66 us with WRITE dominating.
__global__ __launch_bounds__(256) void precompute_v11(
        const int* __restrict__ x, const float* __restrict__ emb,
        const float* __restrict__ W_rnn, const float* __restrict__ b_rnn,
        __hip_bfloat16* __restrict__ P) {
    const int tid = threadIdx.x;
    const int jj  = tid & 31;
    const int l   = tid & 63;
    const int grp = tid >> 5;
    const int g   = (blockIdx.x * 256 + tid) >> 5;
    const int pair0 = g * 16;

    __shared__ float stage[8][16][HH];

    float wx[32];
#pragma unroll
    for (int k = 0; k < 32; ++k) wx[k] = W_rnn[k * HH + jj];
    const float bj = b_rnn[jj];

    const int idxv  = x[pair0 + (jj & 15)];
    const int bbase = (l & 32) * 4;

    float ev[16];
#pragma unroll
    for (int i = 0; i < 16; ++i) {
        int pi = __builtin_amdgcn_ds_bpermute(bbase + 4 * i, idxv);
        ev[i] = emb[(size_t)pi * HH + jj];
    }
#pragma unroll
    for (int i = 0; i < 16; ++i)
        stage[grp][i][jj] = ev[i];

#pragma unroll 4
    for (int i = 0; i < 16; ++i) {
        const float4* sp = (const float4*)&stage[grp][i][0];
        float u0 = bj, u1 = 0.f, u2 = 0.f, u3 = 0.f;
#pragma unroll
        for (int q = 0; q < 8; ++q) {
            float4 e = sp[q];
            u0 = fmaf(e.x, wx[4*q+0], u0);
            u1 = fmaf(e.y, wx[4*q+1], u1);
            u2 = fmaf(e.z, wx[4*q+2], u2);
            u3 = fmaf(e.w, wx[4*q+3], u3);
        }
        P[(size_t)(pair0 + i) * HH + jj] = __float2bfloat16((u0 + u1) + (u2 + u3));
    }
}

// ---------------- Pass 2: k-split scan (R9-exact structure; bf16 P loads) --------------
// Lane l: r=l>>5 (row), q=(l>>4)&1 (k-half), i=l&15. Lane owns h[q*16+i].
// One 15-DPP rotation stream feeds keep- and send-partials; ONE ds_swizzle xor16
// exchanges the k-half partials (latency hidden under the keep tree); one tanh/lane.
// P ring is converted bf16->f32 at fill time (outside the step), so the step-loop
// chain is identical to R9 (best measured: 308 us, 360 cyc/step, 72% issue-occ).
__global__ __launch_bounds__(64, 1) void rnn_seq_v11(
        const __hip_bfloat16* __restrict__ P, const float* __restrict__ W_rnn,
        const float* __restrict__ W_cls, const float* __restrict__ b_cls,
        float* __restrict__ out) {
    const int l = threadIdx.x;
    const int i = l & 15;
    const int q = (l >> 4) & 1;

    // Direction probe (validated R6-R10: absmax 0.0).
    int rt = __builtin_amdgcn_mov_dpp(i, 0x121, 0xF, 0xF, false);
    const int d = (rt == ((i + 1) & 15)) ? 1 : -1;

    float wKeep[16], wSend[16];
#pragma unroll
    for (int o = 0; o < 16; ++o) {
        const int k = q * 16 + ((i + d * o) & 15);
        wKeep[o] = W_rnn[(HH + k) * HH + (q * 16 + i)];
        wSend[o] = W_rnn[(HH + k) * HH + ((q ^ 1) * 16 + i)];
    }
#pragma unroll
    for (int o = 0; o < 16; ++o) { PIN(wKeep[o]); PIN(wSend[o]); }

    // p address: row*HH + q*16 + i = blk*64 + l (contiguous 128B per wave-load).
    const __hip_bfloat16* gp = P + (size_t)blockIdx.x * 64 + l;

    float pA[8], pB[8];
#pragma unroll
    for (int t = 0; t < 8; ++t)
        pA[t] = __bfloat162float(gp[(size_t)t * PSTRIDE]);

    float h = 0.0f;

    auto step = [&](float p) {
        float rot[16];
        rot[0] = h;
        rot[1] = dpp_ror<1>(h);
        rot[2] = dpp_ror<2>(h);
        rot[3] = dpp_ror<3>(h);
#pragma unroll
        for (int m = 1; m < 4; ++m) {
            rot[4*m+0] = dpp_ror<4>(rot[4*m-4]);
            rot[4*m+1] = dpp_ror<4>(rot[4*m-3]);
            rot[4*m+2] = dpp_ror<4>(rot[4*m-2]);
            rot[4*m+3] = dpp_ror<4>(rot[4*m-1]);
        }
        // Send partial first, swizzle it out early (latency hides under keep tree).
        float s0 = rot[0] * wSend[0], s1 = rot[1] * wSend[1];
        float s2 = rot[2] * wSend[2], s3 = rot[3] * wSend[3];
#pragma unroll
        for (int m = 1; m < 4; ++m) {
            s0 = fmaf(rot[4*m+0], wSend[4*m+0], s0);
            s1 = fmaf(rot[4*m+1], wSend[4*m+1], s1);
            s2 = fmaf(rot[4*m+2], wSend[4*m+2], s2);
            s3 = fmaf(rot[4*m+3], wSend[4*m+3], s3);
        }
        float send = (s0 + s1) + (s2 + s3);
        float recv = swz_x16(send);
        float k0 = fmaf(rot[0], wKeep[0], p), k1 = rot[1] * wKeep[1];
        float k2 = rot[2] * wKeep[2],         k3 = rot[3] * wKeep[3];
#pragma unroll
        for (int m = 1; m < 4; ++m) {
            k0 = fmaf(rot[4*m+0], wKeep[4*m+0], k0);
            k1 = fmaf(rot[4*m+1], wKeep[4*m+1], k1);
            k2 = fmaf(rot[4*m+2], wKeep[4*m+2], k2);
            k3 = fmaf(rot[4*m+3], wKeep[4*m+3], k3);
        }
        float u = ((k0 + k1) + (k2 + k3)) + recv;
        h = fast_tanh(u);
    };

#pragma unroll 1
    for (int e = 0; e < TT / 16; ++e) {
        const int tB = e * 16 + 8;
#pragma unroll
        for (int t = 0; t < 8; ++t)
            pB[t] = __bfloat162float(gp[(size_t)(tB + t) * PSTRIDE]);
#pragma unroll
        for (int t = 0; t < 8; ++t) PIN(pA[t]);
#pragma unroll
        for (int s = 0; s < 8; ++s) step(pA[s]);

        int tA = e * 16 + 16;
        if (tA > TT - 8) tA = TT - 8;   // tail reload redundant but in-bounds
#pragma unroll
        for (int t = 0; t < 8; ++t)
            pA[t] = __bfloat162float(gp[(size_t)(tA + t) * PSTRIDE]);
#pragma unroll
        for (int t = 0; t < 8; ++t) PIN(pB[t]);
#pragma unroll
        for (int s = 0; s < 8; ++s) step(pB[s]);
    }

    // Epilogue: hf[l] = h lands exactly at hf[r*32 + q*16 + i]; 10 lanes store y.
    __shared__ float hf[64];
    hf[l] = h;
    if (l < 10) {
        const int rr = l / 5, c = l % 5;
        float acc = b_cls[c];
#pragma unroll
        for (int k = 0; k < 32; ++k)
            acc = fmaf(hf[rr * 32 + k], W_cls[k * 5 + c], acc);
        out[(blockIdx.x * 2 + rr) * 5 + c] = acc;
    }
}

// ---------------- Fallback (fused) for tiny workspace ----------------------------------
__device__ __forceinline__ float rnn_step_fb(const float4 xt[8], const float wx[32],
                                             const float wh[32], float bj,
                                             float* hrow, int lane) {
    float u0 = 0.f, u1 = 0.f, u2 = 0.f, u3 = 0.f;
#pragma unroll
    for (int q = 0; q < 8; ++q) {
        u0 = fmaf(xt[q].x, wx[4*q+0], u0);
        u1 = fmaf(xt[q].y, wx[4*q+1], u1);
        u2 = fmaf(xt[q].z, wx[4*q+2], u2);
        u3 = fmaf(xt[q].w, wx[4*q+3], u3);
    }
    const float4* hp = (const float4*)hrow;
#pragma unroll
    for (int q = 0; q < 8; ++q) {
        float4 hv = hp[q];
        u0 = fmaf(hv.x, wh[4*q+0], u0);
        u1 = fmaf(hv.y, wh[4*q+1], u1);
        u2 = fmaf(hv.z, wh[4*q+2], u2);
        u3 = fmaf(hv.w, wh[4*q+3], u3);
    }
    float hn = fast_tanh(bj + ((u0 + u1) + (u2 + u3)));
    hrow[lane] = hn;
    return hn;
}

__global__ __launch_bounds__(64, 1) void rnn_seq_kernel(
        const int* __restrict__ x, const float* __restrict__ emb,
        const float* __restrict__ W_rnn, const float* __restrict__ b_rnn,
        const float* __restrict__ W_cls, const float* __restrict__ b_cls,
        float* __restrict__ out) {
    const int lane = threadIdx.x & 31;
    const int grp  = threadIdx.x >> 5;
    const int row  = blockIdx.x * 2 + grp;
    __shared__ float hbuf[2][HH];
    float wx[32], wh[32];
#pragma unroll
    for (int k = 0; k < 32; ++k) {
        wx[k] = W_rnn[k * HH + lane];
        wh[k] = W_rnn[(HH + k) * HH + lane];
    }
    const float bj = b_rnn[lane];
    hbuf[grp][lane] = 0.0f;
    float* hrow = &hbuf[grp][0];
    int i1 = x[1 * BB + row];
    float4 xcur[8], xnxt[8];
    {
        int i0 = x[0 * BB + row];
        const float4* ep = (const float4*)(emb + (size_t)i0 * HH);
#pragma unroll
        for (int q = 0; q < 8; ++q) xcur[q] = ep[q];
    }
    for (int t = 0; t < TT; t += 2) {
        int i2 = x[min(t + 2, TT - 1) * BB + row];
        {
            const float4* ep = (const float4*)(emb + (size_t)i1 * HH);
#pragma unroll
            for (int q = 0; q < 8; ++q) xnxt[q] = ep[q];
        }
        rnn_step_fb(xcur, wx, wh, bj, hrow, lane);
        i1 = x[min(t + 3, TT - 1) * BB + row];
        {
            const float4* ep = (const float4*)(emb + (size_t)i2 * HH);
#pragma unroll
            for (int q = 0; q < 8; ++q) xcur[q] = ep[q];
        }
        rnn_step_fb(xnxt, wx, wh, bj, hrow, lane);
    }
    if (lane < 5) {
        float acc = b_cls[lane];
#pragma unroll
        for (int k = 0; k < 32; ++k)
            acc = fmaf(hrow[k], W_cls[k * 5 + lane], acc);
        out[row * 5 + lane] = acc;
    }
}

extern "C" void kernel_launch(void* const* d_in, const int* in_sizes, int n_in,
                              void* d_out, int out_size, void* d_ws, size_t ws_size,
                              hipStream_t stream) {
    const int*   x     = (const int*)d_in[0];
    const float* emb   = (const float*)d_in[1];
    const float* W_rnn = (const float*)d_in[2];
    const float* b_rnn = (const float*)d_in[3];
    const float* W_cls = (const float*)d_in[4];
    const float* b_cls = (const float*)d_in[5];
    float* out = (float*)d_out;

    const size_t need16 = (size_t)NPAIR * HH * 2;   // 64 MiB (bf16 P)
    if (ws_size >= need16) {
        __hip_bfloat16* P = (__hip_bfloat16*)d_ws;
        const int pre_blocks = NPAIR / (16 * 8);    // 8192 blocks x 256 thr
        precompute_v11<<<pre_blocks, 256, 0, stream>>>(x, emb, W_rnn, b_rnn, P);
        rnn_seq_v11<<<BB / 2, 64, 0, stream>>>(P, W_rnn, W_cls, b_cls, out);
    } else {
        rnn_seq_kernel<<<BB / 2, 64, 0, stream>>>(x, emb, W_rnn, b_rnn, W_cls, b_cls, out);
    }
}